// Round 1
// baseline (115.691 us; speedup 1.0000x reference)
//
#include <hip/hip_runtime.h>
#include <math.h>

// Tropical (max-plus) depthwise conv2d, 5x5, stride 1, pad 2, dilation 1.
// x: (8,32,224,224) f32, kernel: (32,1,5,5) f32, out: (8,32,224,224) f32.
// out[b,c,h,w] = max_{i,j} x[b,c,h-2+i, w-2+j] + kernel[c,0,4-i,4-j]
//
// R7: drop LDS staging entirely. Block working set (20 rows x 896 B ~= 18 KB)
// fits in the 32 KB L1, so the LDS round-trip + vmcnt(0) barrier drain of R6
// bought nothing: every thread now loads its 8-float tap window per input row
// directly from global as float2+float4+float2 (32 B vs R6's 48 B staged).
// Neighbor-lane overlap = L1 hits; wave/block halo rows = L2/L3 hits.
// No __syncthreads, no -inf prologue, OOB rows skip compute entirely.
// Edge columns handled by lane-0 / lane-55 cndmask to -inf.

#define TC_B 8
#define TC_C 32
#define TC_H 224
#define TC_W 224
#define TC_WQ 56          // f4 per image row
#define TC_HG 14          // 224/16 row-groups

__global__ __launch_bounds__(256) void tropical_conv2d_kernel(
    const float* __restrict__ x, const float* __restrict__ kern,
    float* __restrict__ out) {
  const int tid = threadIdx.x;
  const int lane = tid & 63;
  const int yl = tid >> 6;          // wave 0..3
  const int blk = blockIdx.x;
  const int hg = blk % TC_HG;
  const int bc = blk / TC_HG;       // b*C + c (uniform)
  const int c = bc & (TC_C - 1);

  const float NEG = -INFINITY;

  // weights: w[i*5+j] = wflip[i][j] = kern[c][4-i][4-j]; c uniform -> s_loads
  float w[25];
  #pragma unroll
  for (int q = 0; q < 25; ++q) w[q] = kern[c * 25 + 24 - q];

  if (lane >= TC_WQ) return;        // 56 data lanes; no staging role anymore

  const float* xp = x + (size_t)bc * (TC_H * TC_W);
  const int hbase = hg * 16 + yl * 4;   // first of this thread's 4 output rows

  float acc[4][4];
  #pragma unroll
  for (int o = 0; o < 4; ++o)
    #pragma unroll
    for (int k = 0; k < 4; ++k) acc[o][k] = NEG;

  const bool ledge = (lane == 0);
  const bool redge = (lane == TC_WQ - 1);
  const int col0 = lane * 4;        // first output col of this thread

  // input row g = hbase - 2 + ri feeds output rows o with i = ri - o in [0,4]
  #pragma unroll
  for (int ri = 0; ri < 8; ++ri) {
    const int g = hbase - 2 + ri;
    if (g < 0 || g >= TC_H) continue;          // wave-uniform branch
    const float* rowp = xp + (size_t)g * TC_W;

    // tap window u[m] = x[g, col0 + m - 2], m = 0..7
    const float4 Bv = *(const float4*)(rowp + col0);            // cols 0..3
    float2 A2, C2;
    if (ledge) { A2 = make_float2(NEG, NEG); }                  // cols -2,-1
    else       { A2 = *(const float2*)(rowp + col0 - 2); }
    if (redge) { C2 = make_float2(NEG, NEG); }                  // cols 224,225
    else       { C2 = *(const float2*)(rowp + col0 + 4); }

    const float u[8] = {A2.x, A2.y, Bv.x, Bv.y, Bv.z, Bv.w, C2.x, C2.y};

    #pragma unroll
    for (int o = 0; o < 4; ++o) {
      const int i = ri - o;                    // weight row (compile-time)
      if (i < 0 || i > 4) continue;
      #pragma unroll
      for (int k = 0; k < 4; ++k) {
        const float m01 = fmaxf(u[k + 0] + w[i * 5 + 0],
                                u[k + 1] + w[i * 5 + 1]);
        const float m23 = fmaxf(u[k + 2] + w[i * 5 + 2],
                                u[k + 3] + w[i * 5 + 3]);
        const float m4  = u[k + 4] + w[i * 5 + 4];
        acc[o][k] = fmaxf(fmaxf(acc[o][k], m01), fmaxf(m23, m4));
      }
    }
  }

  float* op = out + (size_t)bc * (TC_H * TC_W) + (size_t)hbase * TC_W;
  #pragma unroll
  for (int o = 0; o < 4; ++o) {
    ((float4*)(op + (size_t)o * TC_W))[lane] =
        make_float4(acc[o][0], acc[o][1], acc[o][2], acc[o][3]);
  }
}

extern "C" void kernel_launch(void* const* d_in, const int* in_sizes, int n_in,
                              void* d_out, int out_size, void* d_ws, size_t ws_size,
                              hipStream_t stream) {
  const float* x = (const float*)d_in[0];
  const float* k = (const float*)d_in[1];
  float* out = (float*)d_out;

  dim3 block(256, 1, 1);
  dim3 grid(TC_B * TC_C * TC_HG, 1, 1);
  tropical_conv2d_kernel<<<grid, block, 0, stream>>>(x, k, out);
}

// Round 3
// 111.794 us; speedup vs baseline: 1.0349x; 1.0349x over previous
//
#include <hip/hip_runtime.h>
#include <math.h>

// Tropical (max-plus) depthwise conv2d, 5x5, stride 1, pad 2, dilation 1.
// x: (8,32,224,224) f32, kernel: (32,1,5,5) f32, out: (8,32,224,224) f32.
// out[b,c,h,w] = max_{i,j} x[b,c,h-2+i, w-2+j] + kernel[c,0,4-i,4-j]
//
// R9 = R8 with the nontemporal-store compile fix (clang ext_vector_type
// float4 instead of HIP_vector_type). R8 content:
//  1. XCD-chunked blockIdx swizzle: consecutive hg tiles of the same (b,c)
//     plane share 4 halo rows; chunked remap keeps them on one XCD's L2 so
//     the halo isn't re-fetched from HBM (fills flush L3 every iteration,
//     so x is NOT cache-resident -- halo re-fetch is real HBM traffic).
//     3584 % 8 == 0 -> bijective.
//  2. max3-friendly reduction nesting: fmaxf(fmaxf(a,b),c) fuses to
//     v_max3_f32 -> 5 max ops/tap-group -> 3.
//  3. Non-temporal float4 output stores: out is write-once, keep L2 for x.
// (R7 direct-load experiment regressed +5us: 2x wave halo overlap + 3
//  load instrs/row + per-row runtime branch beat the one-barrier staging.)

#define TC_B 8
#define TC_C 32
#define TC_H 224
#define TC_W 224
#define TC_WQ 56          // f4 per image row
#define TC_HG 14          // 224/16 row-groups
#define T_ROWS 20         // 16 data + 2+2 halo rows
#define ROW_F4 65         // LDS row stride in float4
#define ROW_FL (ROW_F4 * 4)
#define NWG (TC_B * TC_C * TC_HG)   // 3584
#define NXCD 8
#define WPX (NWG / NXCD)            // 448, exact

typedef float f4v __attribute__((ext_vector_type(4)));  // NT-store-legal

__global__ __launch_bounds__(256) void tropical_conv2d_kernel(
    const float* __restrict__ x, const float* __restrict__ kern,
    float* __restrict__ out) {
  const int tid = threadIdx.x;
  const int lane = tid & 63;
  const int yl = tid >> 6;          // wave 0..3

  // XCD-chunked swizzle: HW round-robins blockIdx across 8 XCDs; remap so
  // each XCD owns a contiguous range of logical tiles (halo rows L2-hit).
  const int orig = blockIdx.x;
  const int blk = (orig & (NXCD - 1)) * WPX + (orig >> 3);

  const int hg = blk % TC_HG;
  const int bc = blk / TC_HG;       // b*C + c (uniform)
  const int c = bc & (TC_C - 1);

  __shared__ float tile[T_ROWS * ROW_FL];   // 20*65*16 = 20800 B

  const float NEG = -INFINITY;
  const float4 NINF4 = make_float4(NEG, NEG, NEG, NEG);
  const float* xp = x + (size_t)bc * (TC_H * TC_W);

  // left-halo f4 (index 0) of every row = -inf; staging never writes f4 0.
  if (tid < T_ROWS) *(float4*)&tile[tid * ROW_FL] = NINF4;

  // ---- staging: wave yl owns tile rows yl*5 .. yl*5+4 ----
  const int cl = lane < TC_WQ ? lane : TC_WQ - 1;   // clamp spill lanes
  #pragma unroll
  for (int rr = 0; rr < 5; ++rr) {
    const int r = yl * 5 + rr;                      // wave-uniform
    const int g = hg * 16 - 2 + r;                  // global row, uniform
    float* ldsrow = &tile[r * ROW_FL + 4];          // f4 index 1 (uniform base)
    if (g >= 0 && g < TC_H) {
      const float* gp = xp + (size_t)g * TC_W + cl * 4;
      // lane i -> LDS f4 index 1+i, holding x f4 col min(i,55)
      __builtin_amdgcn_global_load_lds(
          (const __attribute__((address_space(1))) void*)gp,
          (__attribute__((address_space(3))) void*)ldsrow, 16, 0, 0);
    } else {
      *(float4*)(ldsrow + (size_t)lane * 4) = NINF4;  // OOB row = -inf
    }
  }

  // weights while staging flies: c uniform -> scalar loads
  // w[i*5+j] = wflip[i][j] = kern[c][4-i][4-j]
  float w[25];
  #pragma unroll
  for (int q = 0; q < 25; ++q) w[q] = kern[c * 25 + 24 - q];

  __syncthreads();   // drains vmcnt (global_load_lds) + lgkmcnt

  if (lane >= TC_WQ) return;

  const int hbase = hg * 16 + yl * 4;   // first of this thread's 4 output rows

  float acc[4][4];
  #pragma unroll
  for (int o = 0; o < 4; ++o)
    #pragma unroll
    for (int k = 0; k < 4; ++k) acc[o][k] = NEG;

  const bool redge = (lane == TC_WQ - 1);

  // tile row (yl*4 + ri) holds input row hbase-2+ri
  #pragma unroll
  for (int ri = 0; ri < 8; ++ri) {
    const float* rp = &tile[(yl * 4 + ri) * ROW_FL + 4 * lane];
    const float4 A = *(const float4*)(rp);        // x cols 4l-4..4l-1 (or -inf halo)
    const float4 Bv = *(const float4*)(rp + 4);   // x cols 4l..4l+3
    const float4 Cv = *(const float4*)(rp + 8);   // x cols 4l+4..4l+7
    float v[12] = {A.x, A.y, A.z, A.w, Bv.x, Bv.y, Bv.z, Bv.w,
                   Cv.x, Cv.y, Cv.z, Cv.w};
    // right edge: f4 57 holds lane-spill garbage, taps use v[8],v[9] only
    v[8] = redge ? NEG : v[8];
    v[9] = redge ? NEG : v[9];

    #pragma unroll
    for (int o = 0; o < 4; ++o) {
      const int i = ri - o;                // weight row (compile-time)
      if (i < 0 || i > 4) continue;
      #pragma unroll
      for (int k = 0; k < 4; ++k) {
        const float t0 = v[2 + k] + w[i * 5 + 0];
        const float t1 = v[3 + k] + w[i * 5 + 1];
        const float t2 = v[4 + k] + w[i * 5 + 2];
        const float t3 = v[5 + k] + w[i * 5 + 3];
        const float t4 = v[6 + k] + w[i * 5 + 4];
        // max3-friendly nesting: (t0,t1,t2) and (t3,t4,acc) -> v_max3 pair
        acc[o][k] = fmaxf(fmaxf(fmaxf(t0, t1), t2),
                          fmaxf(fmaxf(t3, t4), acc[o][k]));
      }
    }
  }

  float* op = out + (size_t)bc * (TC_H * TC_W) + (size_t)hbase * TC_W;
  #pragma unroll
  for (int o = 0; o < 4; ++o) {
    f4v val = {acc[o][0], acc[o][1], acc[o][2], acc[o][3]};
    __builtin_nontemporal_store(val, (f4v*)(op + (size_t)o * TC_W) + lane);
  }
}

extern "C" void kernel_launch(void* const* d_in, const int* in_sizes, int n_in,
                              void* d_out, int out_size, void* d_ws, size_t ws_size,
                              hipStream_t stream) {
  const float* x = (const float*)d_in[0];
  const float* k = (const float*)d_in[1];
  float* out = (float*)d_out;

  dim3 block(256, 1, 1);
  dim3 grid(NWG, 1, 1);
  tropical_conv2d_kernel<<<grid, block, 0, stream>>>(x, k, out);
}

// Round 4
// 111.524 us; speedup vs baseline: 1.0374x; 1.0024x over previous
//
#include <hip/hip_runtime.h>
#include <math.h>

// Tropical (max-plus) depthwise conv2d, 5x5, stride 1, pad 2, dilation 1.
// x: (8,32,224,224) f32, kernel: (32,1,5,5) f32, out: (8,32,224,224) f32.
// out[b,c,h,w] = max_{i,j} x[b,c,h-2+i, w-2+j] + kernel[c,0,4-i,4-j]
//
// R10: taller tile. 32 output rows per block (was 16): halo read
// amplification 1.25 -> 1.125, and each vmcnt(0) barrier drain is
// amortized over 2x the compute. Staging skeleton unchanged from R6
// (global_load_lds 16B, one barrier; R7 showed direct-load is worse).
// Keeps R9's XCD-chunked swizzle + max3 nesting + NT stores (neutral but
// theory-positive, zero cost). LDS 36*65*16 = 37440 B -> 4 blocks/CU,
// 16 waves/CU; in-flight staged rows/CU same as R6 (4*36 ~= 7*20).

#define TC_B 8
#define TC_C 32
#define TC_H 224
#define TC_W 224
#define TC_WQ 56          // f4 per image row
#define TC_HG 7           // 224/32 row-groups
#define T_ROWS 36         // 32 data + 2+2 halo rows
#define ROW_F4 65         // LDS row stride in float4
#define ROW_FL (ROW_F4 * 4)
#define NWG (TC_B * TC_C * TC_HG)   // 1792
#define NXCD 8
#define WPX (NWG / NXCD)            // 224, exact

typedef float f4v __attribute__((ext_vector_type(4)));  // NT-store-legal

__global__ __launch_bounds__(256) void tropical_conv2d_kernel(
    const float* __restrict__ x, const float* __restrict__ kern,
    float* __restrict__ out) {
  const int tid = threadIdx.x;
  const int lane = tid & 63;
  const int yl = tid >> 6;          // wave 0..3

  // XCD-chunked swizzle: each XCD owns a contiguous range of logical tiles.
  const int orig = blockIdx.x;
  const int blk = (orig & (NXCD - 1)) * WPX + (orig >> 3);

  const int hg = blk % TC_HG;
  const int bc = blk / TC_HG;       // b*C + c (uniform)
  const int c = bc & (TC_C - 1);

  __shared__ float tile[T_ROWS * ROW_FL];   // 36*65*16 = 37440 B

  const float NEG = -INFINITY;
  const float4 NINF4 = make_float4(NEG, NEG, NEG, NEG);
  const float* xp = x + (size_t)bc * (TC_H * TC_W);

  // left-halo f4 (index 0) of every row = -inf; staging never writes f4 0.
  if (tid < T_ROWS) *(float4*)&tile[tid * ROW_FL] = NINF4;

  // ---- staging: wave yl owns tile rows yl*9 .. yl*9+8 ----
  const int cl = lane < TC_WQ ? lane : TC_WQ - 1;   // clamp spill lanes
  #pragma unroll
  for (int rr = 0; rr < 9; ++rr) {
    const int r = yl * 9 + rr;                      // wave-uniform
    const int g = hg * 32 - 2 + r;                  // global row, uniform
    float* ldsrow = &tile[r * ROW_FL + 4];          // f4 index 1 (uniform base)
    if (g >= 0 && g < TC_H) {
      const float* gp = xp + (size_t)g * TC_W + cl * 4;
      // lane i -> LDS f4 index 1+i, holding x f4 col min(i,55)
      __builtin_amdgcn_global_load_lds(
          (const __attribute__((address_space(1))) void*)gp,
          (__attribute__((address_space(3))) void*)ldsrow, 16, 0, 0);
    } else {
      *(float4*)(ldsrow + (size_t)lane * 4) = NINF4;  // OOB row = -inf
    }
  }

  // weights while staging flies: c uniform -> scalar loads
  // w[i*5+j] = wflip[i][j] = kern[c][4-i][4-j]
  float w[25];
  #pragma unroll
  for (int q = 0; q < 25; ++q) w[q] = kern[c * 25 + 24 - q];

  __syncthreads();   // drains vmcnt (global_load_lds) + lgkmcnt

  if (lane >= TC_WQ) return;

  const int hbase = hg * 32 + yl * 8;   // first of this thread's 8 output rows

  float acc[8][4];
  #pragma unroll
  for (int o = 0; o < 8; ++o)
    #pragma unroll
    for (int k = 0; k < 4; ++k) acc[o][k] = NEG;

  const bool redge = (lane == TC_WQ - 1);

  // tile row (yl*8 + ri) holds input row hbase-2+ri, ri = 0..11
  #pragma unroll
  for (int ri = 0; ri < 12; ++ri) {
    const float* rp = &tile[(yl * 8 + ri) * ROW_FL + 4 * lane];
    const float4 A = *(const float4*)(rp);        // x cols 4l-4..4l-1 (or -inf halo)
    const float4 Bv = *(const float4*)(rp + 4);   // x cols 4l..4l+3
    const float4 Cv = *(const float4*)(rp + 8);   // x cols 4l+4..4l+7
    float v[12] = {A.x, A.y, A.z, A.w, Bv.x, Bv.y, Bv.z, Bv.w,
                   Cv.x, Cv.y, Cv.z, Cv.w};
    // right edge: f4 57 holds lane-spill garbage, taps use v[8],v[9] only
    v[8] = redge ? NEG : v[8];
    v[9] = redge ? NEG : v[9];

    #pragma unroll
    for (int o = 0; o < 8; ++o) {
      const int i = ri - o;                // weight row (compile-time)
      if (i < 0 || i > 4) continue;
      #pragma unroll
      for (int k = 0; k < 4; ++k) {
        const float t0 = v[2 + k] + w[i * 5 + 0];
        const float t1 = v[3 + k] + w[i * 5 + 1];
        const float t2 = v[4 + k] + w[i * 5 + 2];
        const float t3 = v[5 + k] + w[i * 5 + 3];
        const float t4 = v[6 + k] + w[i * 5 + 4];
        // max3-friendly nesting: (t0,t1,t2) and (t3,t4,acc) -> v_max3 pair
        acc[o][k] = fmaxf(fmaxf(fmaxf(t0, t1), t2),
                          fmaxf(fmaxf(t3, t4), acc[o][k]));
      }
    }
  }

  float* op = out + (size_t)bc * (TC_H * TC_W) + (size_t)hbase * TC_W;
  #pragma unroll
  for (int o = 0; o < 8; ++o) {
    f4v val = {acc[o][0], acc[o][1], acc[o][2], acc[o][3]};
    __builtin_nontemporal_store(val, (f4v*)(op + (size_t)o * TC_W) + lane);
  }
}

extern "C" void kernel_launch(void* const* d_in, const int* in_sizes, int n_in,
                              void* d_out, int out_size, void* d_ws, size_t ws_size,
                              hipStream_t stream) {
  const float* x = (const float*)d_in[0];
  const float* k = (const float*)d_in[1];
  float* out = (float*)d_out;

  dim3 block(256, 1, 1);
  dim3 grid(NWG, 1, 1);
  tropical_conv2d_kernel<<<grid, block, 0, stream>>>(x, k, out);
}